// Round 4
// baseline (155.475 us; speedup 1.0000x reference)
//
#include <hip/hip_runtime.h>
#include <hip/hip_bf16.h>

// SEQ=512, BATCH=64, DIM=512, MAXLEN=512, E=655360
// out[b][u][s] = edge(b,u,s) ? exp(scale) / (T_e + 1e-10*(T-T_e)) : 0   (max cancels)
// scale[s,b,m] = sum_d M[s,b,d] * W[m,d]
// Block = (b, m-tile 64) x full s=512. 512 threads (8 waves, one s-64-chunk each).
// BK=32, single-buffer LDS (pitch 40 ushort = 80B: conflict-free b128 r/w),
// 512 blocks = 2/CU so barrier-anti-phased blocks overlap stage vs MFMA.

#define SEQ 512
#define BATCH 64
#define DIM 512
#define MAXLEN 512

typedef __attribute__((ext_vector_type(8))) __bf16 bf16x8;
typedef __attribute__((ext_vector_type(4))) float f32x4;

__device__ __forceinline__ unsigned cvt_pk(float lo, float hi) {
    unsigned r;
    asm("v_cvt_pk_bf16_f32 %0, %1, %2" : "=v"(r) : "v"(lo), "v"(hi));
    return r;
}

// ---------------- edge bitmap scatter ----------------
__global__ __launch_bounds__(256) void edge_scatter(const int* __restrict__ eb,
                                                    const int* __restrict__ eu,
                                                    const int* __restrict__ ev,
                                                    unsigned int* __restrict__ bits,
                                                    int E) {
    int i = blockIdx.x * 256 + threadIdx.x;
    if (i < E) {
        int b = eb[i], u = eu[i], v = ev[i];
        atomicOr(&bits[(b * MAXLEN + u) * 16 + (v >> 5)], 1u << (v & 31));
    }
}

// ---------------- fused GEMM + softmax + edge renorm ----------------
__global__ __launch_bounds__(512, 4) void fused_attn(const float* __restrict__ Mg,
                                                     const float* __restrict__ Wg,
                                                     const unsigned int* __restrict__ bitsG,
                                                     float* __restrict__ out) {
    __shared__ __align__(16) unsigned short At[64 * 40];    //  5120 B
    __shared__ __align__(16) unsigned short Bt[512 * 40];   // 40960 B
    __shared__ float2 red[64][8];                           //  4096 B

    // XCD-concentrating remap: all 8 m-tiles of a b land on one XCD (g&7)
    const int g = blockIdx.x;
    const int work = (g & 7) * 64 + (g >> 3);   // bijective over [0,512)
    const int b  = work >> 3;
    const int m0 = (work & 7) * 64;

    const int t    = threadIdx.x;
    const int lane = t & 63;
    const int ws   = t >> 6;       // wave id = s chunk (64 cols each)
    const int lg   = lane >> 4;    // 0..3
    const int lc   = lane & 15;

    const float* mrow = Mg + (size_t)t * (BATCH * DIM) + (size_t)b * DIM; // s-row t
    const float* arow = Wg + (size_t)(m0 + (t >> 3)) * DIM + (t & 7) * 4;
    unsigned short* awp = At + (t >> 3) * 40 + (t & 7) * 4;
    unsigned short* bwp = Bt + t * 40;

    f32x4 acc[4][4] = {};   // [m-frag i][s-frag j]

    for (int k0 = 0; k0 < DIM; k0 += 32) {
        // ---- stage A: one float4 per thread ----
        float4 a4 = *reinterpret_cast<const float4*>(arow + k0);
        uint2 ap;
        ap.x = cvt_pk(a4.x, a4.y); ap.y = cvt_pk(a4.z, a4.w);
        *reinterpret_cast<uint2*>(awp) = ap;

        // ---- stage B: own s-row, 32 k's = 8 float4, in two half-batches ----
#pragma unroll
        for (int h = 0; h < 2; ++h) {
            float4 b0 = *reinterpret_cast<const float4*>(mrow + k0 + h * 16);
            float4 b1 = *reinterpret_cast<const float4*>(mrow + k0 + h * 16 + 4);
            float4 b2 = *reinterpret_cast<const float4*>(mrow + k0 + h * 16 + 8);
            float4 b3 = *reinterpret_cast<const float4*>(mrow + k0 + h * 16 + 12);
            uint4 p0, p1;
            p0.x = cvt_pk(b0.x, b0.y); p0.y = cvt_pk(b0.z, b0.w);
            p0.z = cvt_pk(b1.x, b1.y); p0.w = cvt_pk(b1.z, b1.w);
            p1.x = cvt_pk(b2.x, b2.y); p1.y = cvt_pk(b2.z, b2.w);
            p1.z = cvt_pk(b3.x, b3.y); p1.w = cvt_pk(b3.z, b3.w);
            *reinterpret_cast<uint4*>(bwp + h * 16)     = p0;
            *reinterpret_cast<uint4*>(bwp + h * 16 + 8) = p1;
        }
        __syncthreads();

        // ---- fragments + MFMA ----
        bf16x8 af[4], bfr[4];
#pragma unroll
        for (int i = 0; i < 4; ++i)
            af[i] = *reinterpret_cast<const bf16x8*>(At + (i * 16 + lc) * 40 + lg * 8);
#pragma unroll
        for (int j = 0; j < 4; ++j)
            bfr[j] = *reinterpret_cast<const bf16x8*>(Bt + (ws * 64 + j * 16 + lc) * 40 + lg * 8);
#pragma unroll
        for (int i = 0; i < 4; ++i)
#pragma unroll
            for (int j = 0; j < 4; ++j)
                acc[i][j] = __builtin_amdgcn_mfma_f32_16x16x32_bf16(af[i], bfr[j], acc[i][j], 0, 0, 0);
        __syncthreads();
    }

    // ---- epilogue: sum-only softmax (max cancels) + edge renorm ----
    // acc[i][j][r]: m-row = i*16 + lg*4 + r, s-col = ws*64 + j*16 + lc
#pragma unroll
    for (int i = 0; i < 4; ++i) {
#pragma unroll
        for (int r = 0; r < 4; ++r) {
            int m = i * 16 + lg * 4 + r;
            uint2 wb = *reinterpret_cast<const uint2*>(
                bitsG + ((size_t)(b * MAXLEN + m0 + m)) * 16 + ws * 2);
            float T = 0.f, Te = 0.f;
#pragma unroll
            for (int j = 0; j < 4; ++j) {
                float e = __expf(acc[i][j][r]);
                acc[i][j][r] = e;
                unsigned word = (j < 2) ? wb.x : wb.y;
                float bit = (float)((word >> ((j & 1) * 16 + lc)) & 1u);
                T += e; Te += e * bit;
            }
#pragma unroll
            for (int off = 1; off < 16; off <<= 1) {
                T  += __shfl_xor(T, off);
                Te += __shfl_xor(Te, off);
            }
            if (lc == 0) red[m][ws] = make_float2(T, Te);
        }
    }
    __syncthreads();

#pragma unroll
    for (int i = 0; i < 4; ++i) {
#pragma unroll
        for (int r = 0; r < 4; ++r) {
            int m = i * 16 + lg * 4 + r;
            float T = 0.f, Te = 0.f;
#pragma unroll
            for (int q = 0; q < 8; ++q) {
                float2 p = red[m][q];
                T += p.x; Te += p.y;
            }
            float inv = 1.0f / (Te + 1e-10f * (T - Te));
            uint2 wb = *reinterpret_cast<const uint2*>(
                bitsG + ((size_t)(b * MAXLEN + m0 + m)) * 16 + ws * 2);
            size_t base = ((size_t)(b * MAXLEN + m0 + m)) * SEQ + ws * 64 + lc;
#pragma unroll
            for (int j = 0; j < 4; ++j) {
                unsigned word = (j < 2) ? wb.x : wb.y;
                unsigned bit = (word >> ((j & 1) * 16 + lc)) & 1u;
                out[base + j * 16] = bit ? acc[i][j][r] * inv : 0.0f;
            }
        }
    }
}

extern "C" void kernel_launch(void* const* d_in, const int* in_sizes, int n_in,
                              void* d_out, int out_size, void* d_ws, size_t ws_size,
                              hipStream_t stream) {
    const float* Mg = (const float*)d_in[0];
    const float* Wg = (const float*)d_in[1];
    // d_in[2] = lengths (unused by reference)
    const int* eb = (const int*)d_in[3];
    const int* eu = (const int*)d_in[4];
    const int* ev = (const int*)d_in[5];
    const int E = in_sizes[3];

    float* out = (float*)d_out;
    unsigned int* bits = (unsigned int*)d_ws;   // 32768 rows * 16 words = 2 MB

    hipMemsetAsync(bits, 0, (size_t)BATCH * MAXLEN * 16 * sizeof(unsigned int), stream);
    edge_scatter<<<(E + 255) / 256, 256, 0, stream>>>(eb, eu, ev, bits, E);
    fused_attn<<<512, 512, 0, stream>>>(Mg, Wg, bits, out);
}

// Round 6
// 92.202 us; speedup vs baseline: 1.6862x; 1.6862x over previous
//
#include <hip/hip_runtime.h>
#include <hip/hip_bf16.h>

// SEQ=512, BATCH=64, DIM=512, MAXLEN=512, E=655360
// out[b][u][s] = edge(b,u,s) ? exp(scale) / (T_e + 1e-10*(T-T_e)) : 0  (max cancels)
// scale[s,b,m] = sum_d M[s,b,d] * W[m,d]
// Block = (b, m-tile 64) x full s=512; 8 waves, wave wv owns s-band wv*64..+63.
// B (M, f32) DMA'd per-wave via global_load_lds (no barrier: bands are
// wave-private, guarded by per-wave vmcnt). A (W, bf16 pre-converted) is
// double-buffered, one barrier/step. XOR swizzle folded into DMA source addr.

#define SEQ 512
#define BATCH 64
#define DIM 512
#define MAXLEN 512

typedef __attribute__((ext_vector_type(8))) __bf16 bf16x8;
typedef __attribute__((ext_vector_type(4))) float f32x4;

__device__ __forceinline__ unsigned cvt_pk(float lo, float hi) {
    unsigned r;
    asm("v_cvt_pk_bf16_f32 %0, %1, %2" : "=v"(r) : "v"(lo), "v"(hi));
    return r;
}

__device__ __forceinline__ void gload16(const void* g, void* l) {
    __builtin_amdgcn_global_load_lds(
        (const __attribute__((address_space(1))) void*)g,
        (__attribute__((address_space(3))) void*)l, 16, 0, 0);
}

// ---------------- edge bitmap scatter ----------------
__global__ __launch_bounds__(256) void edge_scatter(const int* __restrict__ eb,
                                                    const int* __restrict__ eu,
                                                    const int* __restrict__ ev,
                                                    unsigned int* __restrict__ bits,
                                                    int E) {
    int i = blockIdx.x * 256 + threadIdx.x;
    if (i < E) {
        int b = eb[i], u = eu[i], v = ev[i];
        atomicOr(&bits[(b * MAXLEN + u) * 16 + (v >> 5)], 1u << (v & 31));
    }
}

// ---------------- W f32 -> bf16 (once) ----------------
__global__ __launch_bounds__(256) void cvt_w(const float* __restrict__ src,
                                             unsigned short* __restrict__ dst) {
    int i = blockIdx.x * 256 + threadIdx.x;          // 0..32767, 8 floats each
    const float4* s = (const float4*)src + (size_t)i * 2;
    float4 a = s[0], c = s[1];
    uint4 o;
    o.x = cvt_pk(a.x, a.y); o.y = cvt_pk(a.z, a.w);
    o.z = cvt_pk(c.x, c.y); o.w = cvt_pk(c.z, c.w);
    ((uint4*)dst)[i] = o;
}

// ---------------- fused GEMM + softmax + edge renorm ----------------
__global__ __launch_bounds__(512, 4) void fused_attn(
    const float* __restrict__ Mg,
    const unsigned short* __restrict__ Wbf,
    const unsigned int* __restrict__ bitsG,
    float* __restrict__ out) {
    __shared__ __align__(16) char lds[81920];
    char* bufB  = lds;                               // 64 KB: [512][128B] f32 swz
    char* curA  = lds + 65536;                       // 4 KB bf16 [64][64B] swz
    char* nxtA  = lds + 69632;                       // 4 KB
    float2* red = (float2*)(lds + 73728);            // [64][8]
    unsigned* bitsL = (unsigned*)(lds + 77824);      // [64][16]
    float* stg = (float*)lds;                        // epilogue [16][516]

    // XCD-concentrating remap: all 8 m-tiles of a b on one XCD
    const int g = blockIdx.x;
    const int work = (g & 7) * 64 + (g >> 3);   // bijective over [0,512)
    const int b  = work >> 3;
    const int m0 = (work & 7) * 64;

    const int t = threadIdx.x;
    const int lane = t & 63;
    const int wv = t >> 6;      // wave = s band
    const int lg = lane >> 4;   // 0..3
    const int lc = lane & 15;

    // stage edge bits (one-time; prologue barrier covers)
    if (t < 256)
        ((uint4*)bitsL)[t] = ((const uint4*)(bitsG + (size_t)(b * MAXLEN + m0) * 16))[t];

    // per-lane DMA source swizzle components
    const int brs = lane >> 3;                 // B row-sub 0..7
    const int bc  = (lane & 7) ^ brs;          // B source chunk for own LDS slot
    const int ars = lane >> 2;                 // A row-sub 0..15
    const int ac  = (lane & 3) ^ ((ars >> 2) & 3);

    const char* const MgB = (const char*)Mg + (size_t)b * DIM * 4;
    const char* const WbB = (const char*)Wbf + (size_t)m0 * DIM * 2;

    f32x4 acc[4][4] = {};

    // prologue: A(ks=0)
    if (wv < 4)
        gload16(WbB + (size_t)(wv * 16 + ars) * (DIM * 2) + ac * 16,
                curA + wv * 16 * 64);
    __syncthreads();

#pragma unroll 2
    for (int ks = 0; ks < 16; ++ks) {
        const int kb = ks * 128;   // BK=32 f32 = 128 B
        // 1) own B band: 8 DMA insts (rows wv*64+q*8+brs)
#pragma unroll
        for (int q = 0; q < 8; ++q) {
            int r = wv * 64 + q * 8 + brs;
            gload16(MgB + (size_t)r * (BATCH * DIM * 4) + kb + bc * 16,
                    bufB + (wv * 64 + q * 8) * 128);
        }
        // 2) A(ks+1) prefetch (stays in flight across the wait)
        const bool pfA = (ks < 15) && (wv < 4);
        if (pfA)
            gload16(WbB + (size_t)(wv * 16 + ars) * (DIM * 2) + (ks + 1) * 64 + ac * 16,
                    nxtA + wv * 16 * 64);
        // 3) wait own B only (A may stay outstanding)
        if (pfA) asm volatile("s_waitcnt vmcnt(1)" ::: "memory");
        else     asm volatile("s_waitcnt vmcnt(0)" ::: "memory");

        // 4) fragments + MFMA
        const int fxr = (lc >> 2) & 3;
        bf16x8 af[4];
#pragma unroll
        for (int i = 0; i < 4; ++i)
            af[i] = *(const bf16x8*)(curA + (i * 16 + lc) * 64 + ((lg ^ fxr) * 16));
        const int bxr = lc & 7;
        bf16x8 bfr[4];
#pragma unroll
        for (int j = 0; j < 4; ++j) {
            const char* rowp = bufB + (wv * 64 + j * 16 + lc) * 128;
            f32x4 x = *(const f32x4*)(rowp + (((2 * lg) ^ bxr) * 16));
            f32x4 y = *(const f32x4*)(rowp + (((2 * lg + 1) ^ bxr) * 16));
            uint4 pk;
            pk.x = cvt_pk(x[0], x[1]); pk.y = cvt_pk(x[2], x[3]);
            pk.z = cvt_pk(y[0], y[1]); pk.w = cvt_pk(y[2], y[3]);
            bfr[j] = __builtin_bit_cast(bf16x8, pk);
        }
#pragma unroll
        for (int i = 0; i < 4; ++i)
#pragma unroll
            for (int j = 0; j < 4; ++j)
                acc[i][j] = __builtin_amdgcn_mfma_f32_16x16x32_bf16(af[i], bfr[j], acc[i][j], 0, 0, 0);
        __syncthreads();   // A(ks+1) landed; curA free for restage
        { char* tmp = curA; curA = nxtA; nxtA = tmp; }
    }

    // ---- epilogue pass 1: exp + per-wave (T,Te) partials ----
#pragma unroll
    for (int i = 0; i < 4; ++i) {
#pragma unroll
        for (int r = 0; r < 4; ++r) {
            const int m = i * 16 + lg * 4 + r;
            const uint2 wbt = *(const uint2*)(bitsL + m * 16 + wv * 2);
            float T = 0.f, Te = 0.f;
#pragma unroll
            for (int j = 0; j < 4; ++j) {
                float e = __expf(acc[i][j][r]);
                acc[i][j][r] = e;
                unsigned word = (j & 2) ? wbt.y : wbt.x;
                float bit = (float)((word >> ((j & 1) * 16 + lc)) & 1u);
                T += e; Te += e * bit;
            }
#pragma unroll
            for (int off = 1; off < 16; off <<= 1) {
                T  += __shfl_xor(T, off);
                Te += __shfl_xor(Te, off);
            }
            if (lc == 0) red[m * 8 + wv] = make_float2(T, Te);
        }
    }
    __syncthreads();

    // ---- epilogue pass 2: masked scale -> LDS transpose -> coalesced store ----
    for (int i = 0; i < 4; ++i) {
        float inv[4];
        uint2 wbt2[4];
#pragma unroll
        for (int r = 0; r < 4; ++r) {
            const int m = i * 16 + lg * 4 + r;
            float T = 0.f, Te = 0.f;
#pragma unroll
            for (int q = 0; q < 8; ++q) {
                float2 p = red[m * 8 + q];
                T += p.x; Te += p.y;
            }
            inv[r] = 1.0f / (Te + 1e-10f * (T - Te));
            wbt2[r] = *(const uint2*)(bitsL + m * 16 + wv * 2);
        }
#pragma unroll
        for (int r = 0; r < 4; ++r) {
#pragma unroll
            for (int j = 0; j < 4; ++j) {
                unsigned word = (j & 2) ? wbt2[r].y : wbt2[r].x;
                unsigned bit = (word >> ((j & 1) * 16 + lc)) & 1u;
                stg[(lg * 4 + r) * 516 + wv * 64 + j * 16 + lc] =
                    bit ? acc[i][j][r] * inv[r] : 0.0f;
            }
        }
        __syncthreads();
#pragma unroll
        for (int it = 0; it < 4; ++it) {
            int f = it * 512 + t;
            int ml = f >> 7;
            int s4 = (f & 127) * 4;
            float4 v = *(const float4*)(stg + ml * 516 + s4);
            *(float4*)(out + ((size_t)(b * MAXLEN + m0 + i * 16 + ml)) * SEQ + s4) = v;
        }
        __syncthreads();
    }
}

extern "C" void kernel_launch(void* const* d_in, const int* in_sizes, int n_in,
                              void* d_out, int out_size, void* d_ws, size_t ws_size,
                              hipStream_t stream) {
    const float* Mg = (const float*)d_in[0];
    const float* Wg = (const float*)d_in[1];
    // d_in[2] = lengths (unused by reference)
    const int* eb = (const int*)d_in[3];
    const int* eu = (const int*)d_in[4];
    const int* ev = (const int*)d_in[5];
    const int E = in_sizes[3];

    float* out = (float*)d_out;
    unsigned int* bits = (unsigned int*)d_ws;                       // 2 MB
    unsigned short* Wbf = (unsigned short*)((char*)d_ws + 2097152); // 0.5 MB

    hipMemsetAsync(bits, 0, (size_t)BATCH * MAXLEN * 16 * sizeof(unsigned int), stream);
    edge_scatter<<<(E + 255) / 256, 256, 0, stream>>>(eb, eu, ev, bits, E);
    cvt_w<<<128, 256, 0, stream>>>(Wg, Wbf);
    fused_attn<<<512, 512, 0, stream>>>(Mg, Wbf, bits, out);
}